// Round 2
// baseline (383.144 us; speedup 1.0000x reference)
//
#include <hip/hip_runtime.h>
#include <stdint.h>

// CRF forward loss. One block per batch element (serial scan over T).
// Waves 0-5: compute (48 cols x 8 lanes). Waves 6-7: loaders via
// global_load_lds into a 6-deep LDS ring, counted vmcnt (never 0),
// raw s_barrier (no __syncthreads -> no vmcnt(0) pipeline drain).

#define T_LEN 512
#define KK 48
#define ROWPAD 52              // padded row stride (floats): 52 ≡ 20 mod 32 -> <=2-way LDS conflict (free)
#define SLOT_BYTES 10240       // 48*52*4=9984 padded to 10 chunks of 1024B
#define STEP_BYTES 9216        // real bytes per step (48*48*4)
#define DEPTH 6                // ring depth; prefetch distance 5 steps
#define NSTART 46
#define NEND 47

__device__ __forceinline__ void load_lds16(const void* g, void* l) {
  // dest = wave-uniform base + lane*16 (HW); src is per-lane.
  __builtin_amdgcn_global_load_lds(
      (const __attribute__((address_space(1))) uint32_t*)g,
      (__attribute__((address_space(3))) uint32_t*)l, 16, 0, 0);
}

__global__ __launch_bounds__(512) void crf_fwd(
    const float* __restrict__ scores, const int* __restrict__ targets,
    const void* __restrict__ mask, float* __restrict__ out) {
  __shared__ __align__(16) unsigned char ring[DEPTH * SLOT_BYTES]; // 61440 B
  __shared__ int tgt_s[T_LEN];                                     // 2048 B
  __shared__ float alpha_s[2][64];                                 // 512 B
  __shared__ int len_s;

  const int b = blockIdx.x;
  const int tid = threadIdx.x;
  const int wid = tid >> 6;
  const int lane = tid & 63;
  const float* scores_b = scores + (size_t)b * (size_t)(T_LEN * KK * KK);

  // stage targets row (512 threads, 512 ints)
  tgt_s[tid] = targets[b * T_LEN + tid];

  // length = count of prefix-mask ones. The mask is a numpy bool array whose
  // device representation is harness-defined; detect it from the first 8
  // bytes (unambiguous since len[b] >= 256 -> mask[0][0..7] are all ones):
  //   u8  -> w0 = 0x01010101
  //   f32 -> w0 = 0x3F800000 (1.0f)
  //   i32 -> w0 = 1, w1 = 1
  //   i64 -> w0 = 1, w1 = 0
  if (wid == 0) {
    const uint32_t w0 = ((const uint32_t*)mask)[0];
    const uint32_t w1 = ((const uint32_t*)mask)[1];
    int c = 0;
    if (w0 == 0x01010101u) {  // u8 bool
      const unsigned long long* m8 =
          (const unsigned long long*)((const unsigned char*)mask +
                                      (size_t)b * T_LEN);
      c = (int)__popcll(m8[lane]);  // 8 bytes/lane, values 0/1
    } else if (w0 == 0x3F800000u) {  // f32
      const float* mf = (const float*)mask + (size_t)b * T_LEN;
#pragma unroll
      for (int j = 0; j < 8; ++j) c += (mf[lane + 64 * j] != 0.0f);
    } else if (w1 == 1u) {  // i32
      const uint32_t* mi = (const uint32_t*)mask + (size_t)b * T_LEN;
#pragma unroll
      for (int j = 0; j < 8; ++j) c += (mi[lane + 64 * j] != 0u);
    } else {  // i64
      const unsigned long long* ml =
          (const unsigned long long*)mask + (size_t)b * T_LEN;
#pragma unroll
      for (int j = 0; j < 8; ++j) c += (ml[lane + 64 * j] != 0ull);
    }
    c += __shfl_xor(c, 1);
    c += __shfl_xor(c, 2);
    c += __shfl_xor(c, 4);
    c += __shfl_xor(c, 8);
    c += __shfl_xor(c, 16);
    c += __shfl_xor(c, 32);
    if (lane == 0) len_s = (c > T_LEN) ? T_LEN : (c < 0 ? 0 : c);
  }

  const int loader = (wid >= 6);
  const int base_c = (wid - 6) * 5;  // wave6: chunks 0-4, wave7: chunks 5-9
  int goff[5];
  if (loader) {
    // per-lane global byte offset implementing the 48->52 row padding:
    // LDS byte y (linear) <- global byte r*192 + cc ; pad lanes clamp to 0.
    // (208 = 13*16, so every 16B LDS span is within one row or pure pad.)
#pragma unroll
    for (int ci = 0; ci < 5; ++ci) {
      int y = (base_c + ci) * 1024 + lane * 16;
      int r = y / 208;           // 208 = 52 floats * 4B
      int cc = y - r * 208;
      goff[ci] = (r < KK && cc < KK * 4) ? (r * (KK * 4) + cc) : 0;
    }
    // prologue: prefetch steps 0..DEPTH-1 (len >= 256 > DEPTH always)
    for (int d = 0; d < DEPTH; ++d) {
      const unsigned char* gstep =
          (const unsigned char*)scores_b + (size_t)d * STEP_BYTES;
      unsigned char* sb = ring + d * SLOT_BYTES;
#pragma unroll
      for (int ci = 0; ci < 5; ++ci)
        load_lds16(gstep + goff[ci], sb + (base_c + ci) * 1024);
    }
  }
  asm volatile("s_waitcnt lgkmcnt(0)" ::: "memory");
  __builtin_amdgcn_s_barrier();
  asm volatile("" ::: "memory");

  const int len = len_s;
  const int a = lane >> 3;   // 0..7 -> column within wave's 8
  const int l = lane & 7;    // 0..7 -> row subgroup
  const int k = 8 * wid + a; // column 0..47 (compute waves only)
  float gold = 0.0f;
  int slot = 0;

  for (int t = 0; t < len; ++t) {
    // loaders: ensure this step's 5 chunks landed (5 newer steps may remain
    // in flight: 5 chunks * (DEPTH-1) = 25). Compute waves have no vmem.
    if (loader) asm volatile("s_waitcnt vmcnt(25)" ::: "memory");
    __builtin_amdgcn_s_barrier();          // barrier1: slot t published
    asm volatile("" ::: "memory");

    const float* S = (const float*)(ring + slot * SLOT_BYTES);
    if (!loader) {
      if (t == 0) {
        if (l == 0) alpha_s[1][k] = S[NSTART * ROWPAD + k];
      } else {
        const float* aC = alpha_s[t & 1];
        float v[6];
#pragma unroll
        for (int i = 0; i < 6; ++i)
          v[i] = S[(l + 8 * i) * ROWPAD + k] + aC[l + 8 * i];
        float m = v[0];
#pragma unroll
        for (int i = 1; i < 6; ++i) m = fmaxf(m, v[i]);
        m = fmaxf(m, __shfl_xor(m, 1));
        m = fmaxf(m, __shfl_xor(m, 2));
        m = fmaxf(m, __shfl_xor(m, 4));
        const float C1 = 1.4426950408889634f;   // log2(e)
        float mc = m * C1;
        float s = 0.0f;
#pragma unroll
        for (int i = 0; i < 6; ++i) s += exp2f(__builtin_fmaf(v[i], C1, -mc));
        s += __shfl_xor(s, 1);
        s += __shfl_xor(s, 2);
        s += __shfl_xor(s, 4);
        if (l == 0)
          alpha_s[(t + 1) & 1][k] =
              __builtin_fmaf(0.69314718055994531f, log2f(s), m);
      }
    } else if (tid == 511) {
      int tg = tgt_s[t];
      int r = tg / 48;
      int cc = tg - r * 48;
      gold += S[r * ROWPAD + cc];
    }

    asm volatile("s_waitcnt lgkmcnt(0)" ::: "memory"); // publish alpha writes
    __builtin_amdgcn_s_barrier();          // barrier2: slot t free to overwrite
    asm volatile("" ::: "memory");

    if (loader) {
      // constant issue rate (clamped step) keeps the vmcnt immediate exact,
      // including at the tail. Dead prefetches past len are never consumed.
      int nstep = t + DEPTH;
      if (nstep > T_LEN - 1) nstep = T_LEN - 1;
      const unsigned char* gstep =
          (const unsigned char*)scores_b + (size_t)nstep * STEP_BYTES;
      unsigned char* sb = ring + slot * SLOT_BYTES;
#pragma unroll
      for (int ci = 0; ci < 5; ++ci)
        load_lds16(gstep + goff[ci], sb + (base_c + ci) * 1024);
    }
    slot = (slot == DEPTH - 1) ? 0 : slot + 1;
  }

  // drain outstanding LDS-DMA before workgroup retires (LDS reuse safety)
  if (loader) asm volatile("s_waitcnt vmcnt(0)" ::: "memory");
  if (tid == 511) out[b] = (len > 0) ? (alpha_s[len & 1][NEND] - gold) : 0.0f;
}

extern "C" void kernel_launch(void* const* d_in, const int* in_sizes, int n_in,
                              void* d_out, int out_size, void* d_ws,
                              size_t ws_size, hipStream_t stream) {
  const float* scores = (const float*)d_in[0];
  const int* targets = (const int*)d_in[1];
  const void* mask = (const void*)d_in[2];
  float* out = (float*)d_out;
  const int B = in_sizes[1] / T_LEN;  // targets is B*T ints
  crf_fwd<<<B, 512, 0, stream>>>(scores, targets, mask, out);
}

// Round 3
// 93.093 us; speedup vs baseline: 4.1157x; 4.1157x over previous
//
#include <hip/hip_runtime.h>
#include <stdint.h>

// CRF forward loss via chunked parallel scan in linear space.
// K1: len (mask decode) + gold gather.  K2: per-chunk matrix product
// M_c = prod exp(S_t) with bf16 MFMA, one wave per chunk (2048 waves).
// K3: per-batch serial combine of 32 chunk matrices.

#define T_LEN 512
#define KK 48
#define CHUNK 16
#define NCH_PER_B 32
#define NSTART 46
#define NEND 47

#define E_PITCH 104       // bytes, bf16 row pitch for E (64 rows)
#define M_PITCH 112       // bytes, bf16 row pitch for M (49 rows, 16B-mult)
#define E_BYTES (64 * E_PITCH)               // 6656
#define M_OFF   E_BYTES
#define WAVE_LDS (E_BYTES + 49 * M_PITCH)    // 6656 + 5488 = 12144 (16B mult)
#define CHUNK_M_BYTES 4608                   // 48*48 bf16

typedef __attribute__((ext_vector_type(8))) short short8;
typedef __attribute__((ext_vector_type(4))) float f32x4;

__device__ __forceinline__ ushort f2bf(float x) {
  uint32_t u = __float_as_uint(x);
  return (ushort)((u + 0x7FFFu + ((u >> 16) & 1u)) >> 16);
}
__device__ __forceinline__ float bf2f(uint32_t h) {
  return __uint_as_float(h << 16);
}

// ---------------- K1: lengths + gold ----------------
__global__ __launch_bounds__(64) void k1_len_gold(
    const float* __restrict__ scores, const int* __restrict__ targets,
    const void* __restrict__ mask, int* __restrict__ wsLen,
    float* __restrict__ wsGold) {
  const int b = blockIdx.x;
  const int lane = threadIdx.x & 63;

  // detect mask encoding from first 8 bytes (len>=1 -> leading ones)
  const uint32_t w0 = ((const uint32_t*)mask)[0];
  const uint32_t w1 = ((const uint32_t*)mask)[1];
  int c = 0;
  if (w0 == 0x01010101u) {  // u8 bool
    const unsigned long long* m8 =
        (const unsigned long long*)((const unsigned char*)mask + (size_t)b * T_LEN);
    c = (int)__popcll(m8[lane]);
  } else if (w0 == 0x3F800000u) {  // f32
    const float* mf = (const float*)mask + (size_t)b * T_LEN;
#pragma unroll
    for (int j = 0; j < 8; ++j) c += (mf[lane + 64 * j] != 0.0f);
  } else if (w1 == 1u) {  // i32
    const uint32_t* mi = (const uint32_t*)mask + (size_t)b * T_LEN;
#pragma unroll
    for (int j = 0; j < 8; ++j) c += (mi[lane + 64 * j] != 0u);
  } else {  // i64
    const unsigned long long* ml =
        (const unsigned long long*)mask + (size_t)b * T_LEN;
#pragma unroll
    for (int j = 0; j < 8; ++j) c += (ml[lane + 64 * j] != 0ull);
  }
#pragma unroll
  for (int d = 1; d < 64; d <<= 1) c += __shfl_xor(c, d);
  int len = c > T_LEN ? T_LEN : (c < 0 ? 0 : c);

  float g = 0.0f;
  const float* sb = scores + (size_t)b * (T_LEN * KK * KK);
#pragma unroll
  for (int j = 0; j < 8; ++j) {
    int t = j * 64 + lane;
    if (t < len) {
      int tg = targets[b * T_LEN + t];
      g += sb[(size_t)t * (KK * KK) + tg];
    }
  }
#pragma unroll
  for (int d = 1; d < 64; d <<= 1) g += __shfl_xor(g, d);
  if (lane == 0) { wsLen[b] = len; wsGold[b] = g; }
}

// ---------------- K2: chunk products ----------------
__global__ __launch_bounds__(256) void k2_chunks(
    const float* __restrict__ scores, const int* __restrict__ wsLen,
    float* __restrict__ wsOffs, unsigned char* __restrict__ wsM, int nchunks) {
  __shared__ __align__(16) unsigned char smem[4][WAVE_LDS];
  const int wid = threadIdx.x >> 6;
  const int lane = threadIdx.x & 63;
  const int g = blockIdx.x * 4 + wid;
  if (g >= nchunks) return;
  const int b = g >> 5;          // /NCH_PER_B
  const int cix = g & 31;
  const int len = wsLen[b];
  int steps = len - (cix << 4);
  if (steps <= 0) return;        // chunk entirely masked: never consumed
  if (steps > CHUNK) steps = CHUNK;

  unsigned char* wb = smem[wid];          // E region (64 x E_PITCH)
  unsigned char* wm = wb + M_OFF;         // M region (49 x M_PITCH)

  // zero whole wave region once (kills NaN-from-uninit in padded K range)
  {
    int4* z = (int4*)wb;
    const int n16 = WAVE_LDS / 16;  // 759
#pragma unroll
    for (int q = 0; q < 12; ++q) {
      int idx = q * 64 + lane;
      if (idx < n16) z[idx] = make_int4(0, 0, 0, 0);
    }
  }

  const float* tile0 =
      scores + ((size_t)b * T_LEN + (size_t)(cix << 4)) * (KK * KK);
  const float C1 = 1.4426950408889634f;  // log2(e)
  int logE = 0;

  for (int t = 0; t < steps; ++t) {
    // load 9 x float4 of this step's 48x48 tile (coalesced)
    const float4* gp = (const float4*)(tile0 + (size_t)t * (KK * KK));
    float4 fv[9];
#pragma unroll
    for (int i = 0; i < 9; ++i) fv[i] = gp[i * 64 + lane];

    // E = exp(S): pack to bf16 pairs; write to E (t>0) or M (t==0) layout
    uint2 pk[9];
    int ro[9], co[9];
#pragma unroll
    for (int i = 0; i < 9; ++i) {
      float e0 = exp2f(fv[i].x * C1), e1 = exp2f(fv[i].y * C1);
      float e2 = exp2f(fv[i].z * C1), e3 = exp2f(fv[i].w * C1);
      pk[i].x = (uint32_t)f2bf(e0) | ((uint32_t)f2bf(e1) << 16);
      pk[i].y = (uint32_t)f2bf(e2) | ((uint32_t)f2bf(e3) << 16);
      int el = i * 256 + lane * 4;
      ro[i] = el / KK;
      co[i] = el - ro[i] * KK;   // 4-aligned, no row straddle (48%4==0)
    }
    if (t == 0) {
#pragma unroll
      for (int i = 0; i < 9; ++i)
        *(uint2*)(wm + ro[i] * M_PITCH + co[i] * 2) = pk[i];  // M := E_0
      continue;
    }
#pragma unroll
    for (int i = 0; i < 9; ++i)
      *(uint2*)(wb + ro[i] * E_PITCH + co[i] * 2) = pk[i];

    // A-frags from M (row-major b128 reads); K padded to 64 (E rows 48-63 = 0)
    short8 afr[3][2];
#pragma unroll
    for (int mi = 0; mi < 3; ++mi)
#pragma unroll
      for (int ki = 0; ki < 2; ++ki)
        afr[mi][ki] = *(const short8*)(wm + (mi * 16 + (lane & 15)) * M_PITCH +
                                       ki * 64 + (lane >> 4) * 16);
    // B-frags from E (scalar u16 gathers; col n = lane&15, k = (lane>>4)*8+j)
    short8 bfr[2][3];
#pragma unroll
    for (int ki = 0; ki < 2; ++ki)
#pragma unroll
      for (int ni = 0; ni < 3; ++ni) {
        short8 v;
#pragma unroll
        for (int j = 0; j < 8; ++j)
          v[j] = *(const short*)(wb +
                                 (ki * 32 + (lane >> 4) * 8 + j) * E_PITCH +
                                 (ni * 16 + (lane & 15)) * 2);
        bfr[ki][ni] = v;
      }

    f32x4 acc[3][3];
#pragma unroll
    for (int mi = 0; mi < 3; ++mi)
#pragma unroll
      for (int ni = 0; ni < 3; ++ni) {
        f32x4 d = {0.f, 0.f, 0.f, 0.f};
        d = __builtin_amdgcn_mfma_f32_16x16x32_bf16(afr[mi][0], bfr[0][ni], d, 0, 0, 0);
        d = __builtin_amdgcn_mfma_f32_16x16x32_bf16(afr[mi][1], bfr[1][ni], d, 0, 0, 0);
        acc[mi][ni] = d;
      }

    // periodic exact renorm (exponent strip) to keep f32/bf16 in range
    if (((t & 7) == 7) || (t == steps - 1)) {
      float mx = acc[0][0][0];
#pragma unroll
      for (int mi = 0; mi < 3; ++mi)
#pragma unroll
        for (int ni = 0; ni < 3; ++ni)
#pragma unroll
          for (int rr = 0; rr < 4; ++rr) mx = fmaxf(mx, acc[mi][ni][rr]);
#pragma unroll
      for (int d = 1; d < 64; d <<= 1) mx = fmaxf(mx, __shfl_xor(mx, d));
      int ex = (int)((__float_as_uint(mx) >> 23) & 255) - 127;
      float sc = __uint_as_float((uint32_t)(127 - ex) << 23);  // exact 2^-ex
      logE += ex;
#pragma unroll
      for (int mi = 0; mi < 3; ++mi)
#pragma unroll
        for (int ni = 0; ni < 3; ++ni)
#pragma unroll
          for (int rr = 0; rr < 4; ++rr) acc[mi][ni][rr] *= sc;
    }

    // write D -> M (bf16). D layout: col = lane&15, row = (lane>>4)*4+rr [m89]
#pragma unroll
    for (int mi = 0; mi < 3; ++mi)
#pragma unroll
      for (int ni = 0; ni < 3; ++ni)
#pragma unroll
        for (int rr = 0; rr < 4; ++rr) {
          int row = mi * 16 + (lane >> 4) * 4 + rr;
          int col = ni * 16 + (lane & 15);
          *(ushort*)(wm + row * M_PITCH + col * 2) = f2bf(acc[mi][ni][rr]);
        }
  }

  // copy M (48x48 bf16, packed) to global ws
  unsigned char* gd = wsM + (size_t)g * CHUNK_M_BYTES;
#pragma unroll
  for (int jj = 0; jj < 9; ++jj) {
    int flat = (jj * 64 + lane) * 8;     // < 4608
    int row = flat / 96;
    int rem = flat - row * 96;
    *(uint2*)(gd + flat) = *(const uint2*)(wm + row * M_PITCH + rem);
  }
  if (lane == 0) wsOffs[g] = (float)logE * 0.69314718055994531f;
}

// ---------------- K3: per-batch combine ----------------
__global__ __launch_bounds__(64) void k3_combine(
    const unsigned char* __restrict__ wsM, const float* __restrict__ wsOffs,
    const int* __restrict__ wsLen, const float* __restrict__ wsGold,
    float* __restrict__ out) {
  __shared__ float Ms[KK * KK];
  __shared__ float alpha_s[64];
  const int b = blockIdx.x;
  const int lane = threadIdx.x & 63;
  const int len = wsLen[b];
  const int nc = (len + CHUNK - 1) >> 4;

  float a = (lane == NSTART) ? 1.0f : 0.0f;  // linear one-hot start
  int logTi = 0;
  float logF = 0.0f;

  const unsigned char* mb = wsM + (size_t)(b * NCH_PER_B) * CHUNK_M_BYTES;
  uint2 buf[9];
#pragma unroll
  for (int jj = 0; jj < 9; ++jj)
    buf[jj] = *(const uint2*)(mb + (jj * 64 + lane) * 8);

  for (int c = 0; c < nc; ++c) {
    uint2 cur[9];
#pragma unroll
    for (int jj = 0; jj < 9; ++jj) cur[jj] = buf[jj];
    if (c + 1 < nc) {
      const unsigned char* nb = mb + (size_t)(c + 1) * CHUNK_M_BYTES;
#pragma unroll
      for (int jj = 0; jj < 9; ++jj)
        buf[jj] = *(const uint2*)(nb + (jj * 64 + lane) * 8);
    }
    // unpack bf16 -> f32 into LDS [48][48]
#pragma unroll
    for (int jj = 0; jj < 9; ++jj) {
      int e0 = (jj * 64 + lane) * 4;
      f32x4 v;
      v[0] = bf2f(cur[jj].x & 0xFFFFu);
      v[1] = bf2f(cur[jj].x >> 16);
      v[2] = bf2f(cur[jj].y & 0xFFFFu);
      v[3] = bf2f(cur[jj].y >> 16);
      *(f32x4*)(&Ms[e0]) = v;
    }
    alpha_s[lane] = a;
    float s = 0.0f;
    if (lane < KK) {
#pragma unroll 8
      for (int i = 0; i < KK; ++i) s = fmaf(alpha_s[i], Ms[i * KK + lane], s);
    }
    // renorm alpha by exponent strip
    float mx = s;
#pragma unroll
    for (int d = 1; d < 64; d <<= 1) mx = fmaxf(mx, __shfl_xor(mx, d));
    int ex = (int)((__float_as_uint(mx) >> 23) & 255) - 127;
    float sc = __uint_as_float((uint32_t)(127 - ex) << 23);
    a = s * sc;
    logTi += ex;
    logF += wsOffs[b * NCH_PER_B + c];
  }
  if (lane == NEND)
    out[b] = log2f(a) * 0.69314718055994531f +
             (float)logTi * 0.69314718055994531f + logF - wsGold[b];
}

extern "C" void kernel_launch(void* const* d_in, const int* in_sizes, int n_in,
                              void* d_out, int out_size, void* d_ws,
                              size_t ws_size, hipStream_t stream) {
  const float* scores = (const float*)d_in[0];
  const int* targets = (const int*)d_in[1];
  const void* mask = (const void*)d_in[2];
  float* out = (float*)d_out;
  const int B = in_sizes[1] / T_LEN;
  const int nch = B * NCH_PER_B;

  int* wsLen = (int*)d_ws;                          // B ints
  float* wsGold = (float*)d_ws + B;                 // B floats
  float* wsOffs = (float*)d_ws + 2 * B;             // nch floats
  size_t mOff = (size_t)(2 * B + nch) * 4;
  mOff = (mOff + 255) & ~(size_t)255;
  unsigned char* wsM = (unsigned char*)d_ws + mOff; // nch * 4608 bytes

  k1_len_gold<<<B, 64, 0, stream>>>(scores, targets, mask, wsLen, wsGold);
  k2_chunks<<<(nch + 3) / 4, 256, 0, stream>>>(scores, wsLen, wsOffs, wsM, nch);
  k3_combine<<<B, 64, 0, stream>>>(wsM, wsOffs, wsLen, wsGold, out);
}